// Round 5
// baseline (231.988 us; speedup 1.0000x reference)
//
#include <hip/hip_runtime.h>
#include <hip/hip_bf16.h>
#include <cstdint>
#include <cstddef>

constexpr int Bn = 8;
constexpr int Nn = 2048;
constexpr int Dn = 128;

typedef __bf16 bf16x8 __attribute__((ext_vector_type(8)));
typedef float f32x4 __attribute__((ext_vector_type(4)));

// -----------------------------------------------------------------------------
// Kernel 1 (unchanged): h = x@W (fp32), s1 = h@a1, s2 = h@a2, hT bf16 [B][D][N].
// -----------------------------------------------------------------------------
__global__ __launch_bounds__(256) void gat_k1(
    const float* __restrict__ x, const float* __restrict__ W,
    const float* __restrict__ a_vec,
    __bf16* __restrict__ hT, float* __restrict__ s1, float* __restrict__ s2) {
  __shared__ __align__(16) float Wl[64 * 144];  // [k][c-swizzled], 36.9KB
  __shared__ __align__(16) float xL[32 * 132];  // [r][k], 16.9KB

  const int t = threadIdx.x;
  const int r0 = blockIdx.x * 32;
  const int b = r0 >> 11;
  const int n0 = r0 & (Nn - 1);
  const int rp = (t >> 4) << 1;                 // row pair base 0..30
  const int c0 = (t & 15) << 3;                 // 0..120
  const int c0p = c0 + ((c0 >> 5) << 2);        // pad 4 dwords every 32

  float acc[2][8];
#pragma unroll
  for (int r = 0; r < 2; ++r)
#pragma unroll
    for (int c = 0; c < 8; ++c) acc[r][c] = 0.f;

  // stage xL: 32x128 fp32
#pragma unroll
  for (int it = 0; it < 4; ++it) {
    int idx = t + (it << 8);
    int rr = idx >> 5, kc = (idx & 31) << 2;
    *(float4*)(xL + rr * 132 + kc) = *(const float4*)(x + (size_t)(r0 + rr) * Dn + kc);
  }

  for (int ph = 0; ph < 2; ++ph) {
    if (ph) __syncthreads();  // phase-0 readers done before restage
#pragma unroll
    for (int it = 0; it < 8; ++it) {
      int idx = t + (it << 8);
      int kk = idx >> 5, c4 = (idx & 31) << 2;
      int dsto = kk * 144 + c4 + ((c4 >> 5) << 2);
      *(float4*)(Wl + dsto) = *(const float4*)(W + (size_t)((ph << 6) + kk) * Dn + c4);
    }
    __syncthreads();
    const float* xrow = xL + rp * 132 + (ph << 6);
    for (int k = 0; k < 64; ++k) {
      float xa0 = xrow[k];
      float xa1 = xrow[132 + k];
      float4 w0 = *(const float4*)(Wl + k * 144 + c0p);
      float4 w1 = *(const float4*)(Wl + k * 144 + c0p + 4);
      float ws[8] = {w0.x, w0.y, w0.z, w0.w, w1.x, w1.y, w1.z, w1.w};
#pragma unroll
      for (int c = 0; c < 8; ++c) {
        acc[0][c] = fmaf(xa0, ws[c], acc[0][c]);
        acc[1][c] = fmaf(xa1, ws[c], acc[1][c]);
      }
    }
  }

  // s1/s2: partial dots over my 8 cols, reduce across 16 col-groups (lanes&15)
  float q1[2] = {0.f, 0.f}, q2[2] = {0.f, 0.f};
#pragma unroll
  for (int c = 0; c < 8; ++c) {
    float a1c = a_vec[c0 + c];
    float a2c = a_vec[Dn + c0 + c];
    q1[0] = fmaf(acc[0][c], a1c, q1[0]);
    q1[1] = fmaf(acc[1][c], a1c, q1[1]);
    q2[0] = fmaf(acc[0][c], a2c, q2[0]);
    q2[1] = fmaf(acc[1][c], a2c, q2[1]);
  }
#pragma unroll
  for (int d = 1; d < 16; d <<= 1) {
    q1[0] += __shfl_xor(q1[0], d);
    q1[1] += __shfl_xor(q1[1], d);
    q2[0] += __shfl_xor(q2[0], d);
    q2[1] += __shfl_xor(q2[1], d);
  }
  if ((t & 15) == 0) {
    s1[b * Nn + n0 + rp] = q1[0];
    s1[b * Nn + n0 + rp + 1] = q1[1];
    s2[b * Nn + n0 + rp] = q2[0];
    s2[b * Nn + n0 + rp + 1] = q2[1];
  }

  // hT store: rows rp/rp+1 are adjacent n -> pack 2 bf16 per u32
#pragma unroll
  for (int c = 0; c < 8; ++c) {
    union { __bf16 h[2]; uint32_t u; } pk;
    pk.h[0] = (__bf16)acc[0][c];
    pk.h[1] = (__bf16)acc[1][c];
    *(uint32_t*)(hT + (size_t)(b * Dn + c0 + c) * Nn + n0 + rp) = pk.u;
  }
}

// -----------------------------------------------------------------------------
// Kernel 2: 16 i-rows/block, 1024 blocks x 512 thr -> 4 blocks/CU (32 waves).
// No hT LDS staging (L2-resident); B-frags global->VGPR at window top.
// Pl: [16][128] bf16, XOR-swizzled (byte ^= (row&7)<<4) -> 2-way reads (free).
// 16 windows of 128 j; lgkm-only barriers; wave w: d [16w,16w+16) x 16 i.
// __launch_bounds__(512,8): VGPR<=64 (occupancy cliff at 64, m69).
// -----------------------------------------------------------------------------
__global__ __launch_bounds__(512, 8) void gat_k2(
    const int* __restrict__ adj, const __bf16* __restrict__ hT,
    const float* __restrict__ s1, const float* __restrict__ s2,
    float* __restrict__ out, float* __restrict__ alpha) {
  __shared__ __align__(16) float sj[Nn];            // 8 KB
  __shared__ float siv[16], invl[16];
  __shared__ __align__(16) __bf16 Pl[2][16 * 128];  // 8 KB, XOR-swizzled rows

  const int t = threadIdx.x;
  const int b = blockIdx.x >> 7;
  const int i0 = (blockIdx.x & 127) << 4;
  const int w = t >> 6, lane = t & 63;
  const int row = t >> 5;        // i-row 0..15 (32 threads per row)
  const int jl = (t & 31) << 2;  // thread's j offset within a 128-window
  const int q16 = lane >> 4, m16 = lane & 15;
  const int d0 = w << 4;
  const __bf16* __restrict__ hTb = hT + (size_t)b * Dn * Nn;

  *(float4*)(sj + (t << 2)) = *(const float4*)(s2 + b * Nn + (t << 2));
  if (t < 16) siv[t] = s1[b * Nn + i0 + t];
  __syncthreads();

  const int i = i0 + row;
  const int* __restrict__ adjrow = adj + (size_t)i * Nn;
  const float si = siv[row];

  // pass 1: l_i = sum over this thread's j-set (matches alpha-phase mapping);
  // capture adj mask bits into mb0/mb1 (4 bits per window).
  float l = 0.f;
  uint32_t mb0 = 0, mb1 = 0;
#pragma unroll
  for (int k = 0; k < 16; ++k) {
    int j = (k << 7) + jl;
    int4 am = *(const int4*)(adjrow + j);
    float4 sv = *(const float4*)(sj + j);
    float e0 = si + sv.x; e0 = fmaxf(e0, 0.2f * e0);
    float e1 = si + sv.y; e1 = fmaxf(e1, 0.2f * e1);
    float e2 = si + sv.z; e2 = fmaxf(e2, 0.2f * e2);
    float e3 = si + sv.w; e3 = fmaxf(e3, 0.2f * e3);
    l += (am.x > 0) ? __expf(e0) : 0.f;
    l += (am.y > 0) ? __expf(e1) : 0.f;
    l += (am.z > 0) ? __expf(e2) : 0.f;
    l += (am.w > 0) ? __expf(e3) : 0.f;
    uint32_t mbt = (am.x > 0 ? 1u : 0u) | (am.y > 0 ? 2u : 0u) |
                   (am.z > 0 ? 4u : 0u) | (am.w > 0 ? 8u : 0u);
    if (k < 8) mb0 |= mbt << (k << 2);
    else       mb1 |= mbt << ((k & 7) << 2);
  }
  // reduce across the 32 lanes of this i-row (stays within wave half/whole)
  l += __shfl_xor(l, 1);
  l += __shfl_xor(l, 2);
  l += __shfl_xor(l, 4);
  l += __shfl_xor(l, 8);
  l += __shfl_xor(l, 16);
  if ((t & 31) == 0) invl[row] = 1.f / l;
  __syncthreads();
  const float il = invl[row];

  f32x4 acc = {0.f, 0.f, 0.f, 0.f};
  float* __restrict__ arow = alpha + ((size_t)(b * Nn + i) << 11);

  // B-fragment base: lane m16 -> d row, q16 -> 16B j-chunk (16B aligned)
  const __bf16* __restrict__ bp = hTb + (size_t)(d0 + m16) * Nn + (q16 << 3);
  const int swz = (m16 & 7) << 4;

  // alpha phase, window k: exp*il from mask bits, float4 NT store,
  // bf16x4 -> Pl[k&1] at XOR-swizzled byte offset.
  auto alpha_phase = [&](int k) {
    int j = (k << 7) + jl;
    float4 sv = *(const float4*)(sj + j);
    uint32_t mw = (k & 8) ? mb1 : mb0;
    int sh = (k & 7) << 2;
    float e0 = si + sv.x; e0 = fmaxf(e0, 0.2f * e0);
    float e1 = si + sv.y; e1 = fmaxf(e1, 0.2f * e1);
    float e2 = si + sv.z; e2 = fmaxf(e2, 0.2f * e2);
    float e3 = si + sv.w; e3 = fmaxf(e3, 0.2f * e3);
    float a0 = ((mw >> (sh + 0)) & 1u) ? __expf(e0) * il : 0.f;
    float a1 = ((mw >> (sh + 1)) & 1u) ? __expf(e1) * il : 0.f;
    float a2 = ((mw >> (sh + 2)) & 1u) ? __expf(e2) * il : 0.f;
    float a3 = ((mw >> (sh + 3)) & 1u) ? __expf(e3) * il : 0.f;
    f32x4 av = {a0, a1, a2, a3};
    __builtin_nontemporal_store(av, (f32x4*)(arow + j));
    union { __bf16 h[4]; uint2 u2; } pk;
    pk.h[0] = (__bf16)a0; pk.h[1] = (__bf16)a1;
    pk.h[2] = (__bf16)a2; pk.h[3] = (__bf16)a3;
    // row pitch 256B; swizzle flips byte bits 4-6 by (row&7); 8B write
    *(uint2*)((char*)(&Pl[k & 1][0]) + (row << 8) +
              (((jl << 1)) ^ ((row & 7) << 4))) = pk.u2;
  };

  // MFMA window: A rows from Pl[parity] (swizzled), 4 K=32 steps
  auto mfma_win = [&](int parity, bf16x8 c0, bf16x8 c1, bf16x8 c2, bf16x8 c3) {
    const char* plb = (const char*)(&Pl[parity][0]) + (m16 << 8);
    bf16x8 a0 = *(const bf16x8*)(plb + (((0 << 6) + (q16 << 4)) ^ swz));
    bf16x8 a1 = *(const bf16x8*)(plb + (((1 << 6) + (q16 << 4)) ^ swz));
    bf16x8 a2 = *(const bf16x8*)(plb + (((2 << 6) + (q16 << 4)) ^ swz));
    bf16x8 a3 = *(const bf16x8*)(plb + (((3 << 6) + (q16 << 4)) ^ swz));
    acc = __builtin_amdgcn_mfma_f32_16x16x32_bf16(a0, c0, acc, 0, 0, 0);
    acc = __builtin_amdgcn_mfma_f32_16x16x32_bf16(a1, c1, acc, 0, 0, 0);
    acc = __builtin_amdgcn_mfma_f32_16x16x32_bf16(a2, c2, acc, 0, 0, 0);
    acc = __builtin_amdgcn_mfma_f32_16x16x32_bf16(a3, c3, acc, 0, 0, 0);
  };

  // prologue: alpha(0) -> Pl[0]; lgkm-only barrier
  alpha_phase(0);
  asm volatile("s_waitcnt lgkmcnt(0)\n\ts_barrier" ::: "memory");

  // window jt: [load B(jt) | alpha(jt+1) covers load latency | MFMA(jt) |
  // lgkm barrier]. No vmcnt at barriers; TLP (32 waves/CU) absorbs the rest.
#pragma unroll
  for (int jt = 0; jt < 16; ++jt) {
    const __bf16* cp = bp + (jt << 7);
    bf16x8 c0 = *(const bf16x8*)(cp);
    bf16x8 c1 = *(const bf16x8*)(cp + 32);
    bf16x8 c2 = *(const bf16x8*)(cp + 64);
    bf16x8 c3 = *(const bf16x8*)(cp + 96);
    __builtin_amdgcn_sched_barrier(0);  // pin B-load issue first
    if (jt < 15) alpha_phase(jt + 1);
    mfma_win(jt & 1, c0, c1, c2, c3);
    if (jt < 15)
      asm volatile("s_waitcnt lgkmcnt(0)\n\ts_barrier" ::: "memory");
  }

  // epilogue: D row=(q16*4+r) -> i, col=m16 -> d
  int d = d0 + m16;
#pragma unroll
  for (int r = 0; r < 4; ++r) {
    int irow = i0 + (q16 << 2) + r;
    out[((size_t)(b * Nn + irow) << 7) + d] = acc[r];
  }
}

extern "C" void kernel_launch(void* const* d_in, const int* in_sizes, int n_in,
                              void* d_out, int out_size, void* d_ws, size_t ws_size,
                              hipStream_t stream) {
  const float* x = (const float*)d_in[0];
  const int* adj = (const int*)d_in[1];
  const float* W = (const float*)d_in[2];
  const float* a_vec = (const float*)d_in[3];

  float* out = (float*)d_out;
  float* alpha = out + (size_t)Bn * Nn * Dn;  // outputs concatenated: (out, alpha)

  char* ws = (char*)d_ws;
  __bf16* hT = (__bf16*)ws;                               // B*D*N bf16 = 4 MiB
  float* s1 = (float*)(ws + (size_t)Bn * Dn * Nn * 2);    // B*N fp32
  float* s2 = s1 + (size_t)Bn * Nn;                       // B*N fp32

  gat_k1<<<512, 256, 0, stream>>>(x, W, a_vec, hT, s1, s2);
  gat_k2<<<1024, 512, 0, stream>>>(adj, hT, s1, s2, out, alpha);
}